// Round 5
// baseline (97.081 us; speedup 1.0000x reference)
//
#include <hip/hip_runtime.h>
#include <math.h>

#define EPSF 1e-7f
#define NN 512
#define AA 128
#define TT 64
#define NBLK (NN*2)

// 4/pi^2 as computed in double then rounded to f32 (matches jnp promotion)
#define FOUR_OVER_PI2 0.40528473456935109f
#define FLAG_MAGIC 0x1CEB00DAu

__device__ __forceinline__ float fast_rcp(float x) {
    return __builtin_amdgcn_rcpf(x);
}

// Single fused kernel. blockIdx.x = n*2 + s; s selects agents [s*64, s*64+64).
// 256 threads: tid>>2 = local agent (0..63), tid&3 = quarter of the t-range.
// Block NBLK-1 additionally acts as the "finisher": it acquire-polls all 1024
// per-block completion flags (poison-robust: flags carry MAGIC^bid, ws is
// re-poisoned to 0xAA before every call) and reduces the partials into d_out.
// Deadlock-free: only this one block ever waits; all others are independent.
__global__ __launch_bounds__(256, 4) void plan_loss_fused(
    const float* __restrict__ pe,    // pred_ego_traj   (N,T,2)
    const float* __restrict__ te,    // target_ego_traj (N,T,2)
    const float* __restrict__ ebox,  // pred_ego_box_size (N,2)
    const float* __restrict__ abox,  // multiagent_box_sizes (N,A,2)
    const float* __restrict__ atraj, // multiagents_trajs (N,A,T,2)
    float* __restrict__ ws_part,     // [1024] per-block weighted ciou sum / den_n
    float* __restrict__ ws_dist,     // [512]  per-n sum(dist*valid)
    float* __restrict__ ws_valid,    // [512]  per-n sum(valid)
    unsigned int* __restrict__ flags,// [1024] completion flags
    float* __restrict__ out)         // [1] final scalar
{
    __shared__ float s_ex[TT], s_ey[TT];
    __shared__ float s_bx1[TT], s_bx2[TT], s_by1[TT], s_by2[TT];
    __shared__ float s_vf[TT];
    __shared__ float s_awh[64][3], s_ahh[64][3], s_area[64][3], s_v2[64][3], s_opv[64][3];
    __shared__ float s_wsum[4];
    __shared__ float s_den;
    __shared__ float s_fin[3][4];

    const int bid = blockIdx.x;
    const int n   = bid >> 1;
    const int s   = bid & 1;
    const int tid = threadIdx.x;
    const int agentBase = s * 64;

    // ---- issue the big trajectory loads FIRST: latency hides under the
    //      atan precompute (waves 0/1) and the barrier wait (waves 2/3).
    const int la = tid >> 2;
    const int q  = tid & 3;
    const int a  = agentBase + la;
    const float4* tp = reinterpret_cast<const float4*>(
        atraj + ((size_t)(n*AA + a)) * TT * 2) + q * 8;
    float4 p[8];
    #pragma unroll
    for (int j = 0; j < 8; j++) p[j] = tp[j];

    const float ew = ebox[n*2 + 0];
    const float eh = ebox[n*2 + 1];

    if (tid < 64) {
        // --- ego per-timestep precompute + dist/valid reduction (wave 0) ---
        const int t = tid;
        const float px = pe[(n*TT + t)*2 + 0];
        const float py = pe[(n*TT + t)*2 + 1];
        const float tx = te[(n*TT + t)*2 + 0];
        const float ty = te[(n*TT + t)*2 + 1];
        const float vf = (tx != -999.0f && ty != -999.0f) ? 1.0f : 0.0f;
        const float dx = px - tx, dy = py - ty;
        const float dist = sqrtf(dx*dx + dy*dy);
        const float hw = ew * 0.5f, hh = eh * 0.5f;
        s_ex[t] = px;       s_ey[t] = py;
        s_bx1[t] = px - hw; s_bx2[t] = px + hw;
        s_by1[t] = py - hh; s_by2[t] = py + hh;
        s_vf[t] = vf;
        float rd = dist * vf, rv = vf;
        #pragma unroll
        for (int o = 32; o >= 1; o >>= 1) {
            rd += __shfl_xor(rd, o);
            rv += __shfl_xor(rv, o);
        }
        if (t == 0) {
            s_den = rv;
            if (s == 0) {
                __hip_atomic_store(&ws_dist[n],  rd, __ATOMIC_RELAXED, __HIP_MEMORY_SCOPE_AGENT);
                __hip_atomic_store(&ws_valid[n], rv, __ATOMIC_RELAXED, __HIP_MEMORY_SCOPE_AGENT);
            }
        }
    } else if (tid < 128) {
        // --- per-(agent, w) precompute: hoisted atans, areas, half-sizes (wave 1) ---
        const int lla = tid - 64;
        const int aa  = agentBase + lla;
        const float bw = abox[(n*AA + aa)*2 + 0];
        const float bh = abox[(n*AA + aa)*2 + 1];
        const float area1 = ew * eh;
        const float atane = atanf(ew / (eh + EPSF));
        const float tld[3] = {0.0f, 0.0048828125f, 0.009765625f};
        #pragma unroll
        for (int w = 0; w < 3; w++) {
            const float aw = bw + tld[w];
            const float ah = bh + tld[w];
            s_awh[lla][w]  = aw * 0.5f;
            s_ahh[lla][w]  = ah * 0.5f;
            s_area[lla][w] = area1 + aw*ah + EPSF;   // w1h1 + w2h2 + EPS
            const float d = atanf(aw / (ah + EPSF)) - atane;
            const float v = FOUR_OVER_PI2 * d * d;
            s_v2[lla][w]  = v * v;
            s_opv[lla][w] = 1.0f + v + EPSF;         // (1 + v + EPS)
        }
    }
    __syncthreads();

    // register-cache the agent params (15 LDS reads, reused over 16 t-points)
    float awhR[3], ahhR[3], areaR[3], v2R[3], opvR[3];
    #pragma unroll
    for (int w = 0; w < 3; w++) {
        awhR[w]  = s_awh[la][w];
        ahhR[w]  = s_ahh[la][w];
        areaR[w] = s_area[la][w];
        v2R[w]   = s_v2[la][w];
        opvR[w]  = s_opv[la][w];
    }

    float acc0 = 0.0f, acc1 = 0.0f, acc2 = 0.0f;

    #pragma unroll
    for (int j = 0; j < 8; j++) {
        const int t0 = (q*8 + j) * 2;
        #pragma unroll
        for (int half = 0; half < 2; half++) {
            const int t = t0 + half;
            const float ax = half ? p[j].z : p[j].x;
            const float ay = half ? p[j].w : p[j].y;

            const float bx1 = s_bx1[t], bx2 = s_bx2[t];
            const float by1 = s_by1[t], by2 = s_by2[t];
            const float exv = s_ex[t],  eyv = s_ey[t];
            const float vf  = s_vf[t];

            const float ddx = ax - exv, ddy = ay - eyv;
            const float rho2 = ddx*ddx + ddy*ddy;

            float res[3];
            #pragma unroll
            for (int w = 0; w < 3; w++) {
                const float b2x1 = ax - awhR[w], b2x2 = ax + awhR[w];
                const float b2y1 = ay - ahhR[w], b2y2 = ay + ahhR[w];
                float iw = fminf(bx2, b2x2) - fmaxf(bx1, b2x1);
                float ih = fminf(by2, b2y2) - fmaxf(by1, b2y1);
                iw = fmaxf(iw, 0.0f);
                ih = fmaxf(ih, 0.0f);
                const float inter = iw * ih;
                const float uni = areaR[w] - inter;        // union + EPS
                const float iou = inter * fast_rcp(uni);
                const float cw = fmaxf(bx2, b2x2) - fminf(bx1, b2x1);
                const float ch = fmaxf(by2, b2y2) - fminf(by1, b2y1);
                const float c2 = cw*cw + ch*ch + EPSF;
                // iou - rho2/c2 - v^2/(1 - iou + v + EPS)
                res[w] = iou - rho2 * fast_rcp(c2) - v2R[w] * fast_rcp(opvR[w] - iou);
            }
            acc0 += vf * res[0];
            acc1 += vf * res[1];
            acc2 += vf * res[2];
        }
    }

    // weighted combine, then block reduction
    float cacc = acc0 + 0.4f*acc1 + 0.1f*acc2;
    #pragma unroll
    for (int o = 32; o >= 1; o >>= 1) cacc += __shfl_xor(cacc, o);

    const int wave = tid >> 6;
    const int lane = tid & 63;
    if (lane == 0) s_wsum[wave] = cacc;
    __syncthreads();
    if (tid == 0) {
        const float tot = s_wsum[0] + s_wsum[1] + s_wsum[2] + s_wsum[3];
        // publish partial, then release-store the flag (orders all prior
        // writes of this thread, incl. ws_dist/ws_valid, device-wide)
        __hip_atomic_store(&ws_part[bid], tot * fast_rcp(s_den),
                           __ATOMIC_RELAXED, __HIP_MEMORY_SCOPE_AGENT);
        __hip_atomic_store(&flags[bid], FLAG_MAGIC ^ (unsigned)bid,
                           __ATOMIC_RELEASE, __HIP_MEMORY_SCOPE_AGENT);
    }

    // ---- finisher: block NBLK-1 polls all flags, then reduces ----
    if (bid == NBLK - 1) {
        const int f0 = tid * 4;
        #pragma unroll
        for (int k = 0; k < 4; k++) {
            const unsigned f = (unsigned)(f0 + k);
            const unsigned expv = FLAG_MAGIC ^ f;
            while (__hip_atomic_load(&flags[f], __ATOMIC_ACQUIRE,
                                     __HIP_MEMORY_SCOPE_AGENT) != expv) {
                __builtin_amdgcn_s_sleep(2);
            }
        }
        __syncthreads();

        float c = 0.0f, d = 0.0f, v = 0.0f;
        #pragma unroll
        for (int k = 0; k < 4; k++)
            c += __hip_atomic_load(&ws_part[f0 + k], __ATOMIC_RELAXED, __HIP_MEMORY_SCOPE_AGENT);
        #pragma unroll
        for (int k = 0; k < 2; k++) {
            d += __hip_atomic_load(&ws_dist[tid*2 + k],  __ATOMIC_RELAXED, __HIP_MEMORY_SCOPE_AGENT);
            v += __hip_atomic_load(&ws_valid[tid*2 + k], __ATOMIC_RELAXED, __HIP_MEMORY_SCOPE_AGENT);
        }
        #pragma unroll
        for (int o = 32; o >= 1; o >>= 1) {
            c += __shfl_xor(c, o);
            d += __shfl_xor(d, o);
            v += __shfl_xor(v, o);
        }
        if (lane == 0) { s_fin[0][wave] = c; s_fin[1][wave] = d; s_fin[2][wave] = v; }
        __syncthreads();
        if (tid == 0) {
            float Sc = 0.0f, Sd = 0.0f, Sv = 0.0f;
            #pragma unroll
            for (int i = 0; i < 4; i++) {
                Sc += s_fin[0][i]; Sd += s_fin[1][i]; Sv += s_fin[2][i];
            }
            // DIST_LAMBDA * dist_loss + COL_LAMBDA * mean(col); mean over N*A=65536
            out[0] = Sd / Sv + 0.5f * (Sc * (1.0f / 65536.0f));
        }
    }
}

extern "C" void kernel_launch(void* const* d_in, const int* in_sizes, int n_in,
                              void* d_out, int out_size, void* d_ws, size_t ws_size,
                              hipStream_t stream) {
    const float* pe    = (const float*)d_in[0]; // pred_ego_traj
    const float* te    = (const float*)d_in[1]; // target_ego_traj
    const float* ebox  = (const float*)d_in[2]; // pred_ego_box_size
    const float* abox  = (const float*)d_in[3]; // multiagent_box_sizes
    const float* atraj = (const float*)d_in[4]; // multiagents_trajs

    float* wsf            = (float*)d_ws;
    float* ws_part        = wsf;            // 1024
    float* ws_dist        = wsf + 1024;     // 512
    float* ws_valid       = wsf + 1536;     // 512
    unsigned int* flags   = (unsigned int*)(wsf + 2048); // 1024

    plan_loss_fused<<<NBLK, 256, 0, stream>>>(pe, te, ebox, abox, atraj,
                                              ws_part, ws_dist, ws_valid,
                                              flags, (float*)d_out);
}

// Round 6
// 93.854 us; speedup vs baseline: 1.0344x; 1.0344x over previous
//
#include <hip/hip_runtime.h>
#include <math.h>

#define EPSF 1e-7f
#define NN 512
#define AA 128
#define TT 64

// 4/pi^2 as computed in double then rounded to f32 (matches jnp promotion)
#define FOUR_OVER_PI2 0.40528473456935109f

__device__ __forceinline__ float fast_rcp(float x) {
    return __builtin_amdgcn_rcpf(x);
}

// One block per (n, agent-half): blockIdx.x = n*2 + s, s selects agents [s*64, s*64+64)
// 256 threads: tid>>2 = local agent (0..63), tid&3 = quarter of the t-range.
__global__ __launch_bounds__(256) void plan_loss_main(
    const float* __restrict__ pe,    // pred_ego_traj   (N,T,2)
    const float* __restrict__ te,    // target_ego_traj (N,T,2)
    const float* __restrict__ ebox,  // pred_ego_box_size (N,2)
    const float* __restrict__ abox,  // multiagent_box_sizes (N,A,2)
    const float* __restrict__ atraj, // multiagents_trajs (N,A,T,2)
    float* __restrict__ ws_col,      // [1024] per-block weighted ciou sum / denom
    float* __restrict__ ws_dist,     // [512]  per-n sum(dist*valid)
    float* __restrict__ ws_valid)    // [512]  per-n sum(valid)
{
    __shared__ float s_ex[TT], s_ey[TT];
    __shared__ float s_bx1[TT], s_bx2[TT], s_by1[TT], s_by2[TT];
    __shared__ float s_vf[TT];
    __shared__ float s_awh[64][3], s_ahh[64][3], s_area[64][3], s_v2[64][3], s_opv[64][3];
    __shared__ float s_wsum[4];
    __shared__ float s_den;

    const int bid = blockIdx.x;
    const int n   = bid >> 1;
    const int s   = bid & 1;
    const int tid = threadIdx.x;
    const int agentBase = s * 64;

    const float ew = ebox[n*2 + 0];
    const float eh = ebox[n*2 + 1];

    if (tid < 64) {
        // --- ego per-timestep precompute + dist/valid reduction (wave 0) ---
        const int t = tid;
        const float px = pe[(n*TT + t)*2 + 0];
        const float py = pe[(n*TT + t)*2 + 1];
        const float tx = te[(n*TT + t)*2 + 0];
        const float ty = te[(n*TT + t)*2 + 1];
        const float vf = (tx != -999.0f && ty != -999.0f) ? 1.0f : 0.0f;
        const float dx = px - tx, dy = py - ty;
        const float dist = sqrtf(dx*dx + dy*dy);
        const float hw = ew * 0.5f, hh = eh * 0.5f;
        s_ex[t] = px;       s_ey[t] = py;
        s_bx1[t] = px - hw; s_bx2[t] = px + hw;
        s_by1[t] = py - hh; s_by2[t] = py + hh;
        s_vf[t] = vf;
        float rd = dist * vf, rv = vf;
        #pragma unroll
        for (int o = 32; o >= 1; o >>= 1) {
            rd += __shfl_xor(rd, o);
            rv += __shfl_xor(rv, o);
        }
        if (t == 0) {
            s_den = rv;
            if (s == 0) { ws_dist[n] = rd; ws_valid[n] = rv; }
        }
    } else if (tid < 128) {
        // --- per-(agent, w) precompute: hoisted atans, areas, half-sizes (wave 1) ---
        const int la = tid - 64;
        const int a  = agentBase + la;
        const float bw = abox[(n*AA + a)*2 + 0];
        const float bh = abox[(n*AA + a)*2 + 1];
        const float area1 = ew * eh;
        const float atane = atanf(ew / (eh + EPSF));
        const float tld[3] = {0.0f, 0.0048828125f, 0.009765625f};
        #pragma unroll
        for (int w = 0; w < 3; w++) {
            const float aw = bw + tld[w];
            const float ah = bh + tld[w];
            s_awh[la][w]  = aw * 0.5f;
            s_ahh[la][w]  = ah * 0.5f;
            s_area[la][w] = area1 + aw*ah + EPSF;   // w1h1 + w2h2 + EPS
            const float d = atanf(aw / (ah + EPSF)) - atane;
            const float v = FOUR_OVER_PI2 * d * d;
            s_v2[la][w]  = v * v;
            s_opv[la][w] = 1.0f + v + EPSF;         // (1 + v + EPS)
        }
    }
    __syncthreads();

    // --- main loop: each thread owns a quarter of one agent's trajectory ---
    const int la = tid >> 2;
    const int q  = tid & 3;
    const int a  = agentBase + la;

    // register-cache the agent params (15 LDS reads, reused over 16 t-points)
    float awhR[3], ahhR[3], areaR[3], v2R[3], opvR[3];
    #pragma unroll
    for (int w = 0; w < 3; w++) {
        awhR[w]  = s_awh[la][w];
        ahhR[w]  = s_ahh[la][w];
        areaR[w] = s_area[la][w];
        v2R[w]   = s_v2[la][w];
        opvR[w]  = s_opv[la][w];
    }

    const float4* tp = reinterpret_cast<const float4*>(
        atraj + ((size_t)(n*AA + a)) * TT * 2) + q * 8;

    float acc0 = 0.0f, acc1 = 0.0f, acc2 = 0.0f;

    #pragma unroll
    for (int j = 0; j < 8; j++) {
        const float4 p = tp[j];
        const int t0 = (q*8 + j) * 2;

        #pragma unroll
        for (int half = 0; half < 2; half++) {
            const int t = t0 + half;
            const float ax = half ? p.z : p.x;
            const float ay = half ? p.w : p.y;

            const float bx1 = s_bx1[t], bx2 = s_bx2[t];
            const float by1 = s_by1[t], by2 = s_by2[t];
            const float exv = s_ex[t],  eyv = s_ey[t];
            const float vf  = s_vf[t];

            const float ddx = ax - exv, ddy = ay - eyv;
            const float rho2 = ddx*ddx + ddy*ddy;

            float res[3];
            #pragma unroll
            for (int w = 0; w < 3; w++) {
                const float b2x1 = ax - awhR[w], b2x2 = ax + awhR[w];
                const float b2y1 = ay - ahhR[w], b2y2 = ay + ahhR[w];
                float iw = fminf(bx2, b2x2) - fmaxf(bx1, b2x1);
                float ih = fminf(by2, b2y2) - fmaxf(by1, b2y1);
                iw = fmaxf(iw, 0.0f);
                ih = fmaxf(ih, 0.0f);
                const float inter = iw * ih;
                const float uni = areaR[w] - inter;        // union + EPS
                const float iou = inter * fast_rcp(uni);
                const float cw = fmaxf(bx2, b2x2) - fminf(bx1, b2x1);
                const float ch = fmaxf(by2, b2y2) - fminf(by1, b2y1);
                const float c2 = cw*cw + ch*ch + EPSF;
                // iou - rho2/c2 - v^2/(1 - iou + v + EPS)
                res[w] = iou - rho2 * fast_rcp(c2) - v2R[w] * fast_rcp(opvR[w] - iou);
            }
            acc0 += vf * res[0];
            acc1 += vf * res[1];
            acc2 += vf * res[2];
        }
    }

    // weighted combine, then block reduction
    float cacc = 1.0f*acc0 + 0.4f*acc1 + 0.1f*acc2;
    #pragma unroll
    for (int o = 32; o >= 1; o >>= 1) cacc += __shfl_xor(cacc, o);

    const int wave = tid >> 6;
    const int lane = tid & 63;
    if (lane == 0) s_wsum[wave] = cacc;
    __syncthreads();
    if (tid == 0) {
        const float tot = s_wsum[0] + s_wsum[1] + s_wsum[2] + s_wsum[3];
        ws_col[bid] = tot / s_den;   // per-n denom (sum of valid over t)
    }
}

__global__ __launch_bounds__(512) void plan_loss_final(
    const float* __restrict__ ws_col,
    const float* __restrict__ ws_dist,
    const float* __restrict__ ws_valid,
    float* __restrict__ out)
{
    __shared__ float sd[8], sv[8], sc[8];
    const int tid = threadIdx.x;
    float d = ws_dist[tid];
    float v = ws_valid[tid];
    float c = ws_col[tid] + ws_col[tid + 512];
    #pragma unroll
    for (int o = 32; o >= 1; o >>= 1) {
        d += __shfl_xor(d, o);
        v += __shfl_xor(v, o);
        c += __shfl_xor(c, o);
    }
    const int wave = tid >> 6, lane = tid & 63;
    if (lane == 0) { sd[wave] = d; sv[wave] = v; sc[wave] = c; }
    __syncthreads();
    if (tid == 0) {
        float Sd = 0.0f, Sv = 0.0f, Sc = 0.0f;
        #pragma unroll
        for (int i = 0; i < 8; i++) { Sd += sd[i]; Sv += sv[i]; Sc += sc[i]; }
        // DIST_LAMBDA * dist_loss + COL_LAMBDA * mean(col) ; mean over N*A = 65536
        out[0] = 1.0f * (Sd / Sv) + 0.5f * (Sc * (1.0f / 65536.0f));
    }
}

extern "C" void kernel_launch(void* const* d_in, const int* in_sizes, int n_in,
                              void* d_out, int out_size, void* d_ws, size_t ws_size,
                              hipStream_t stream) {
    const float* pe    = (const float*)d_in[0]; // pred_ego_traj
    const float* te    = (const float*)d_in[1]; // target_ego_traj
    const float* ebox  = (const float*)d_in[2]; // pred_ego_box_size
    const float* abox  = (const float*)d_in[3]; // multiagent_box_sizes
    const float* atraj = (const float*)d_in[4]; // multiagents_trajs

    float* wsf      = (float*)d_ws;
    float* ws_col   = wsf;          // 1024
    float* ws_dist  = wsf + 1024;   // 512
    float* ws_valid = wsf + 1536;   // 512

    plan_loss_main<<<NN*2, 256, 0, stream>>>(pe, te, ebox, abox, atraj,
                                             ws_col, ws_dist, ws_valid);
    plan_loss_final<<<1, 512, 0, stream>>>(ws_col, ws_dist, ws_valid, (float*)d_out);
}